// Round 1
// baseline (686.469 us; speedup 1.0000x reference)
//
#include <hip/hip_runtime.h>
#include <math.h>

// Problem constants (from reference): B=8, P=100, N=50000, D=128, TOPK=512
constexpr int kB = 8;
constexpr int kP = 100;
constexpr int kN = 50000;
constexpr int kD = 128;
constexpr int kK = 512;
constexpr int kRows = kB * kP;
constexpr int TN = 128;   // n tile for sim GEMM
constexpr int TKC = 32;   // K chunk for sim GEMM

// Monotonic order-preserving f32 -> u32 key (bijective).
__device__ __forceinline__ unsigned mono_key(float x) {
    unsigned u = __float_as_uint(x);
    return u ^ (unsigned)((((int)u) >> 31) | 0x80000000);
}

// K0: posW[row][e] = sum_d fea0[row][d] * W[d][e]
__global__ void posw_kernel(const float* __restrict__ fea0,
                            const float* __restrict__ W,
                            float* __restrict__ posW) {
    int row = blockIdx.x;      // 0..799
    int e = threadIdx.x;       // 0..127
    __shared__ float a[kD];
    a[e] = fea0[row * kD + e];
    __syncthreads();
    float acc = 0.f;
#pragma unroll 8
    for (int d = 0; d < kD; ++d) acc = fmaf(a[d], W[d * kD + e], acc);
    posW[row * kD + e] = acc;
}

// K1: sim[b][p][n] = fea0[b,p,:] . neg[b,n,:]; store monotonic u32 keys.
// Block computes a 128p x 128n tile (p padded 100->128). 256 thr, 8x8 micro.
__global__ __launch_bounds__(256) void sim_kernel(const float* __restrict__ fea0,
                                                  const float* __restrict__ neg,
                                                  unsigned* __restrict__ keys) {
    __shared__ float As[TKC][128];  // [d][p]
    __shared__ float Bs[TKC][TN];   // [d][n]
    int b = blockIdx.y;
    int n0 = blockIdx.x * TN;
    int tid = threadIdx.x;
    int tx = tid & 15;   // n group
    int ty = tid >> 4;   // p group

    float acc[8][8];
#pragma unroll
    for (int i = 0; i < 8; ++i)
#pragma unroll
        for (int j = 0; j < 8; ++j) acc[i][j] = 0.f;

    const float* fb = fea0 + (size_t)b * kP * kD;
    const float* nb = neg + (size_t)b * kN * kD;

    for (int k0 = 0; k0 < kD; k0 += TKC) {
        // stage A chunk (transpose to [d][p]); zero-pad p >= 100
#pragma unroll
        for (int i = 0; i < 4; ++i) {
            int lin = tid + 256 * i;       // 0..1023
            int p = lin >> 3;              // 0..127
            int d4 = (lin & 7) * 4;        // 0,4,..,28
            float4 v = {0.f, 0.f, 0.f, 0.f};
            if (p < kP) v = *(const float4*)(fb + p * kD + k0 + d4);
            As[d4 + 0][p] = v.x;
            As[d4 + 1][p] = v.y;
            As[d4 + 2][p] = v.z;
            As[d4 + 3][p] = v.w;
        }
        // stage B chunk; zero-pad n >= N (last tile)
#pragma unroll
        for (int i = 0; i < 4; ++i) {
            int lin = tid + 256 * i;
            int n = lin >> 3;
            int d4 = (lin & 7) * 4;
            int gn = n0 + n;
            float4 v = {0.f, 0.f, 0.f, 0.f};
            if (gn < kN) v = *(const float4*)(nb + (size_t)gn * kD + k0 + d4);
            Bs[d4 + 0][n] = v.x;
            Bs[d4 + 1][n] = v.y;
            Bs[d4 + 2][n] = v.z;
            Bs[d4 + 3][n] = v.w;
        }
        __syncthreads();
#pragma unroll
        for (int d = 0; d < TKC; ++d) {
            float av[8], bv[8];
            *(float4*)&av[0] = *(const float4*)&As[d][ty * 8];
            *(float4*)&av[4] = *(const float4*)&As[d][ty * 8 + 4];
            *(float4*)&bv[0] = *(const float4*)&Bs[d][tx * 8];
            *(float4*)&bv[4] = *(const float4*)&Bs[d][tx * 8 + 4];
#pragma unroll
            for (int i = 0; i < 8; ++i)
#pragma unroll
                for (int j = 0; j < 8; ++j)
                    acc[i][j] = fmaf(av[i], bv[j], acc[i][j]);
        }
        __syncthreads();
    }

    bool full = (n0 + TN) <= kN;
#pragma unroll
    for (int i = 0; i < 8; ++i) {
        int p = ty * 8 + i;
        if (p >= kP) continue;
        unsigned* rp = keys + (size_t)(b * kP + p) * kN + n0 + tx * 8;
        if (full) {
            uint4 v0 = {mono_key(acc[i][0]), mono_key(acc[i][1]),
                        mono_key(acc[i][2]), mono_key(acc[i][3])};
            uint4 v1 = {mono_key(acc[i][4]), mono_key(acc[i][5]),
                        mono_key(acc[i][6]), mono_key(acc[i][7])};
            *(uint4*)rp = v0;
            *(uint4*)(rp + 4) = v1;
        } else {
#pragma unroll
            for (int j = 0; j < 8; ++j) {
                int n = n0 + tx * 8 + j;
                if (n < kN) rp[j] = mono_key(acc[i][j]);
            }
        }
    }
}

// K2: per (b,p): exact top-512 selection via key histogram refinement,
// then bilinear rescore of the 512 selected negatives + softmax aggregate.
constexpr int NBIN = 2048;
constexpr int CAND_CAP = 8192;  // expected ~500 in threshold bin
constexpr int TINY_CAP = 128;   // expected ~2-5 at 19-bit refinement

__global__ __launch_bounds__(256) void select_kernel(
    const float* __restrict__ neg,
    const float* __restrict__ posW,
    const unsigned* __restrict__ keys,
    const float* __restrict__ bias_p,
    const float* __restrict__ scale_p,
    float* __restrict__ out) {
    int row = blockIdx.x;  // 0..799
    int b = row / kP;
    int tid = threadIdx.x;

    __shared__ unsigned hist[NBIN];
    __shared__ unsigned seg[256];
    __shared__ unsigned cand[CAND_CAP];
    __shared__ unsigned hist2[256];
    __shared__ unsigned tinybuf[TINY_CAP];
    __shared__ int sel[kK];
    __shared__ float scores[kK];
    __shared__ float pw[kD];
    __shared__ int s_T, s_need1, s_above1, s_candCount;
    __shared__ int s_T2, s_need2, s_above2, s_tinyCount;
    __shared__ unsigned s_Tk;
    __shared__ int s_numGreater, s_eqQuota;
    __shared__ int s_cntG, s_cntE;
    __shared__ float rbuf[8];
    __shared__ float s_m;

    const unsigned* krow = keys + (size_t)row * kN;
    const uint4* krow4 = (const uint4*)krow;  // kN % 4 == 0, row base 16B aligned

    for (int i = tid; i < NBIN; i += 256) hist[i] = 0u;
    if (tid < kD) pw[tid] = posW[row * kD + tid];
    if (tid == 0) { s_candCount = 0; s_tinyCount = 0; s_cntG = 0; s_cntE = 0; }
    __syncthreads();

    // Phase A: 11-bit histogram of keys
    for (int i = tid; i < kN / 4; i += 256) {
        uint4 v = krow4[i];
        atomicAdd(&hist[v.x >> 21], 1u);
        atomicAdd(&hist[v.y >> 21], 1u);
        atomicAdd(&hist[v.z >> 21], 1u);
        atomicAdd(&hist[v.w >> 21], 1u);
    }
    __syncthreads();

    // Phase B: find bin containing the rank-512 boundary (from the top)
    {
        unsigned s = 0;
        int base = tid * 8;
#pragma unroll
        for (int j = 0; j < 8; ++j) s += hist[base + j];
        seg[tid] = s;
    }
    __syncthreads();
    if (tid == 0) {
        unsigned cum = 0;
        int t = 0;
        for (int sg = 255; sg >= 0; --sg) {
            if (cum + seg[sg] >= (unsigned)kK) {
                for (int bi = sg * 8 + 7; bi >= sg * 8; --bi) {
                    if (cum + hist[bi] >= (unsigned)kK) { t = bi; break; }
                    cum += hist[bi];
                }
                break;
            }
            cum += seg[sg];
        }
        s_T = t;
        s_above1 = (int)cum;
        s_need1 = kK - (int)cum;
    }
    __syncthreads();

    // Phase C: collect keys in threshold bin
    unsigned T = (unsigned)s_T;
    for (int i = tid; i < kN / 4; i += 256) {
        uint4 v = krow4[i];
        unsigned kk[4] = {v.x, v.y, v.z, v.w};
#pragma unroll
        for (int c = 0; c < 4; ++c) {
            if ((kk[c] >> 21) == T) {
                int p = atomicAdd(&s_candCount, 1);
                if (p < CAND_CAP) cand[p] = kk[c];
            }
        }
    }
    __syncthreads();
    int cc = min(s_candCount, CAND_CAP);

    // Phase D: refine 8 more bits among candidates
    hist2[tid & 255] = 0u;
    __syncthreads();
    for (int i = tid; i < cc; i += 256) atomicAdd(&hist2[(cand[i] >> 13) & 0xFFu], 1u);
    __syncthreads();
    if (tid == 0) {
        unsigned cum = 0;
        int t2 = 0;
        int need1 = s_need1;
        for (int bi = 255; bi >= 0; --bi) {
            if (cum + hist2[bi] >= (unsigned)need1) { t2 = bi; break; }
            cum += hist2[bi];
        }
        s_T2 = t2;
        s_above2 = (int)cum;
        s_need2 = need1 - (int)cum;
    }
    __syncthreads();

    unsigned T2 = (unsigned)s_T2;
    for (int i = tid; i < cc; i += 256) {
        if (((cand[i] >> 13) & 0xFFu) == T2) {
            int p = atomicAdd(&s_tinyCount, 1);
            if (p < TINY_CAP) tinybuf[p] = cand[i];
        }
    }
    __syncthreads();

    // Exact threshold key among the handful of 19-bit-tied candidates
    if (tid == 0) {
        int tc = min(s_tinyCount, TINY_CAP);
        for (int i = 1; i < tc; ++i) {  // insertion sort desc (tc ~ 2-5)
            unsigned v = tinybuf[i];
            int j = i - 1;
            while (j >= 0 && tinybuf[j] < v) { tinybuf[j + 1] = tinybuf[j]; --j; }
            tinybuf[j + 1] = v;
        }
        int idx = s_need2 - 1;
        if (idx < 0) idx = 0;
        if (idx >= tc) idx = tc - 1;
        unsigned Tk = (tc > 0) ? tinybuf[idx] : 0u;
        int tg = 0;
        while (tg < tc && tinybuf[tg] > Tk) ++tg;
        int numGreater = s_above1 + s_above2 + tg;
        if (numGreater > kK) numGreater = kK;
        s_Tk = Tk;
        s_numGreater = numGreater;
        s_eqQuota = kK - numGreater;
    }
    __syncthreads();

    // Phase E: gather exactly 512 indices (all > Tk, plus quota of == Tk)
    unsigned Tk = s_Tk;
    int nG = s_numGreater;
    int eqQ = s_eqQuota;
    for (int i = tid; i < kN / 4; i += 256) {
        uint4 v = krow4[i];
        unsigned kk[4] = {v.x, v.y, v.z, v.w};
        int nbase = i * 4;
#pragma unroll
        for (int c = 0; c < 4; ++c) {
            unsigned key = kk[c];
            if (key > Tk) {
                int p = atomicAdd(&s_cntG, 1);
                if (p < kK) sel[p] = nbase + c;
            } else if (key == Tk) {
                int p = atomicAdd(&s_cntE, 1);
                if (p < eqQ) {
                    int q = nG + p;
                    if (q < kK) sel[q] = nbase + c;
                }
            }
        }
    }
    __syncthreads();

    // Phase F: bilinear scores for the 512 selected negatives
    const float4* nb4 = (const float4*)(neg + (size_t)b * kN * kD);
#pragma unroll
    for (int r = 0; r < 2; ++r) {
        int k = r * 256 + tid;
        int idx = sel[k];
        if (idx < 0) idx = 0;
        if (idx >= kN) idx = kN - 1;
        const float4* rp = nb4 + (size_t)idx * (kD / 4);
        float acc = 0.f;
#pragma unroll 8
        for (int d4 = 0; d4 < kD / 4; ++d4) {
            float4 nv = rp[d4];
            float4 pv = *(const float4*)&pw[d4 * 4];
            acc = fmaf(nv.x, pv.x, acc);
            acc = fmaf(nv.y, pv.y, acc);
            acc = fmaf(nv.z, pv.z, acc);
            acc = fmaf(nv.w, pv.w, acc);
        }
        scores[k] = acc;
    }
    __syncthreads();

    // Phase G: out = sum softmax(scale*s) * s + bias   (bias shift cancels in softmax)
    float spv = scale_p[0];
    float scale = (spv > 20.f) ? spv : log1pf(__expf(spv));
    int lane = tid & 63;
    int wid = tid >> 6;

    float s0 = scores[tid];
    float s1 = scores[tid + 256];
    float lm = fmaxf(scale * s0, scale * s1);
#pragma unroll
    for (int o = 32; o > 0; o >>= 1) lm = fmaxf(lm, __shfl_down(lm, o));
    if (lane == 0) rbuf[wid] = lm;
    __syncthreads();
    if (tid == 0) s_m = fmaxf(fmaxf(rbuf[0], rbuf[1]), fmaxf(rbuf[2], rbuf[3]));
    __syncthreads();
    float m = s_m;
    float e0 = __expf(scale * s0 - m);
    float e1 = __expf(scale * s1 - m);
    float ln = e0 * s0 + e1 * s1;
    float ld = e0 + e1;
#pragma unroll
    for (int o = 32; o > 0; o >>= 1) {
        ln += __shfl_down(ln, o);
        ld += __shfl_down(ld, o);
    }
    if (lane == 0) { rbuf[wid] = ln; rbuf[4 + wid] = ld; }
    __syncthreads();
    if (tid == 0) {
        float num = rbuf[0] + rbuf[1] + rbuf[2] + rbuf[3];
        float den = rbuf[4] + rbuf[5] + rbuf[6] + rbuf[7];
        out[row] = num / den + bias_p[0];
    }
}

extern "C" void kernel_launch(void* const* d_in, const int* in_sizes, int n_in,
                              void* d_out, int out_size, void* d_ws, size_t ws_size,
                              hipStream_t stream) {
    const float* fea0 = (const float*)d_in[0];       // [8,100,128]
    const float* neg = (const float*)d_in[1];        // [8,50000,128]
    const float* W = (const float*)d_in[2];          // [128,128]
    const float* bias = (const float*)d_in[3];       // scalar
    const float* scale = (const float*)d_in[4];      // scalar
    float* out = (float*)d_out;                      // [800]

    // ws layout: keys (800*50000 u32 = 160 MB) | posW (800*128 f32)
    unsigned* keys = (unsigned*)d_ws;
    float* posW = (float*)((char*)d_ws + (size_t)kRows * kN * sizeof(unsigned));

    posw_kernel<<<kRows, kD, 0, stream>>>(fea0, W, posW);
    sim_kernel<<<dim3((kN + TN - 1) / TN, kB), 256, 0, stream>>>(fea0, neg, keys);
    select_kernel<<<kRows, 256, 0, stream>>>(neg, posW, keys, bias, scale, out);
}

// Round 2
// 490.520 us; speedup vs baseline: 1.3995x; 1.3995x over previous
//
#include <hip/hip_runtime.h>
#include <math.h>

// Problem constants: B=8, P=100, N=50000, D=128, TOPK=512
constexpr int kB = 8;
constexpr int kP = 100;
constexpr int kN = 50000;
constexpr int kD = 128;
constexpr int kK = 512;
constexpr int kRows = kB * kP;

using frag_t = __attribute__((ext_vector_type(8))) short;  // 8 bf16
using f32x4 = __attribute__((ext_vector_type(4))) float;

// Monotonic order-preserving f32 -> u32 key (bijective).
__device__ __forceinline__ unsigned mono32(float x) {
    unsigned u = __float_as_uint(x);
    return u ^ (unsigned)((((int)u) >> 31) | 0x80000000u);
}
__device__ __forceinline__ unsigned short bf16_rne(float x) {
    unsigned u = __float_as_uint(x);
    unsigned r = u + 0x7FFFu + ((u >> 16) & 1u);
    return (unsigned short)(r >> 16);
}

// K0: posW[row] = fea0[row] @ W  (exact f32, sequential-d order) + fea0->bf16 cast
__global__ void posw_kernel(const float* __restrict__ fea0,
                            const float* __restrict__ W,
                            float* __restrict__ posW,
                            unsigned short* __restrict__ feab) {
    int row = blockIdx.x;      // 0..799
    int e = threadIdx.x;       // 0..127
    __shared__ float a[kD];
    float x = fea0[row * kD + e];
    a[e] = x;
    feab[row * kD + e] = bf16_rne(x);
    __syncthreads();
    float acc = 0.f;
#pragma unroll 8
    for (int d = 0; d < kD; ++d) acc = fmaf(a[d], W[d * kD + e], acc);
    posW[row * kD + e] = acc;
}

// K1: approx sims via bf16 MFMA; store u16 monotonic keys.
// Block: 128p (covers all 100, padded) x 128n tile. 4 waves as 2x2 of 64x64.
// MFMA 16x16x32_bf16: A[m=lane&15][k=quad*8+j], B[k][n=lane&15],
//                     D: row(p)=quad*4+reg, col(n)=lane&15.
constexpr int SIM_TN = 128;
__global__ __launch_bounds__(256) void sim_kernel(
    const unsigned short* __restrict__ feab,
    const float* __restrict__ neg,
    unsigned short* __restrict__ keys) {
    __shared__ __align__(16) unsigned short Ah[128][40];  // pad 32->40 (80B rows)
    __shared__ __align__(16) unsigned short Bh[128][40];
    int b = blockIdx.y;
    int n0 = blockIdx.x * SIM_TN;
    int tid = threadIdx.x;
    int lane = tid & 63;
    int wid = tid >> 6;
    int m = lane & 15;
    int q = lane >> 4;
    int wp = (wid >> 1) * 64;
    int wn = (wid & 1) * 64;

    f32x4 acc[4][4];
#pragma unroll
    for (int i = 0; i < 4; ++i)
#pragma unroll
        for (int j = 0; j < 4; ++j) acc[i][j] = (f32x4){0.f, 0.f, 0.f, 0.f};

    const unsigned short* fb = feab + (size_t)b * kP * kD;
    const float* nb = neg + (size_t)b * kN * kD;

    for (int k0 = 0; k0 < kD; k0 += 32) {
        // A tile: 128 rows x 32 bf16 (already converted); 512 16B segments
#pragma unroll
        for (int i = 0; i < 2; ++i) {
            int seg = tid + 256 * i;
            int p = seg >> 2;
            int s8 = (seg & 3) * 8;
            uint4 v = {0u, 0u, 0u, 0u};
            if (p < kP) v = *(const uint4*)(fb + p * kD + k0 + s8);
            *(uint4*)&Ah[p][s8] = v;
        }
        // B tile: 128 rows x 32 f32 -> bf16
#pragma unroll
        for (int i = 0; i < 4; ++i) {
            int lin = tid + 256 * i;
            int n = lin >> 3;
            int k4 = (lin & 7) * 4;
            int gn = n0 + n;
            float4 v = {0.f, 0.f, 0.f, 0.f};
            if (gn < kN) v = *(const float4*)(nb + (size_t)gn * kD + k0 + k4);
            ushort4 h;
            h.x = bf16_rne(v.x);
            h.y = bf16_rne(v.y);
            h.z = bf16_rne(v.z);
            h.w = bf16_rne(v.w);
            *(ushort4*)&Bh[n][k4] = h;
        }
        __syncthreads();
        frag_t af[4], bfr[4];
#pragma unroll
        for (int s = 0; s < 4; ++s) {
            af[s] = *(const frag_t*)&Ah[wp + s * 16 + m][q * 8];
            bfr[s] = *(const frag_t*)&Bh[wn + s * 16 + m][q * 8];
        }
#pragma unroll
        for (int i = 0; i < 4; ++i)
#pragma unroll
            for (int j = 0; j < 4; ++j)
                acc[i][j] = __builtin_amdgcn_mfma_f32_16x16x32_bf16(
                    af[i], bfr[j], acc[i][j], 0, 0, 0);
        __syncthreads();
    }

    // Epilogue: u16 monotonic keys
#pragma unroll
    for (int i = 0; i < 4; ++i) {
        int pbase = wp + i * 16 + q * 4;
#pragma unroll
        for (int j = 0; j < 4; ++j) {
            int n = n0 + wn + j * 16 + m;
            if (n >= kN) continue;
#pragma unroll
            for (int r = 0; r < 4; ++r) {
                int p = pbase + r;
                if (p < kP) {
                    float v = acc[i][j][r];
                    keys[(size_t)(b * kP + p) * kN + n] =
                        (unsigned short)(mono32(v) >> 16);
                }
            }
        }
    }
}

// K2: per (b,p): 13-bit histogram of u16 keys -> threshold bin T.
// bins >= T+2 auto-selected (provably above rank-512 since |err| << bin width);
// bins {T-1,T,T+1} -> exact f32 recompute (numpy order), sort, take remainder.
// Then bilinear rescore of the 512 + softmax aggregate.
constexpr int HB = 8192;   // 13-bit bins
constexpr int CAP = 2048;  // candidate cap (expected ~350)

__global__ __launch_bounds__(256) void select_kernel(
    const float* __restrict__ fea0,
    const float* __restrict__ neg,
    const float* __restrict__ posW,
    const unsigned short* __restrict__ keys,
    const float* __restrict__ bias_p,
    const float* __restrict__ scale_p,
    float* __restrict__ out) {
    int row = blockIdx.x;  // 0..799
    int b = row / kP;
    int tid = threadIdx.x;

    __shared__ union {
        unsigned hist[HB];  // 32 KB, dead after phase B
        struct {
            unsigned long long vals[CAP];  // 16 KB
            unsigned cand[CAP];            // 8 KB
        } s2;
    } u;
    __shared__ unsigned seg[256];
    __shared__ int sel[kK];
    __shared__ float scores[kK];
    __shared__ float pw[kD];
    __shared__ float fr[kD];
    __shared__ int s_T, s_need, s_cnt, s_cc;
    __shared__ float rbuf[8];
    __shared__ float s_m;

    const unsigned short* krow = keys + (size_t)row * kN;
    const uint4* krow4 = (const uint4*)krow;  // 6250 uint4, 16B aligned

    for (int i = tid; i < HB; i += 256) u.hist[i] = 0u;
    if (tid < kD) {
        pw[tid] = posW[row * kD + tid];
        fr[tid] = fea0[row * kD + tid];
    }
    if (tid == 0) { s_cnt = 0; s_cc = 0; }
    __syncthreads();

    // Phase A: histogram (8 u16 keys per uint4)
    for (int i = tid; i < kN / 8; i += 256) {
        uint4 v = krow4[i];
        unsigned w0 = v.x, w1 = v.y, w2 = v.z, w3 = v.w;
        atomicAdd(&u.hist[(w0 & 0xFFFFu) >> 3], 1u);
        atomicAdd(&u.hist[w0 >> 19], 1u);
        atomicAdd(&u.hist[(w1 & 0xFFFFu) >> 3], 1u);
        atomicAdd(&u.hist[w1 >> 19], 1u);
        atomicAdd(&u.hist[(w2 & 0xFFFFu) >> 3], 1u);
        atomicAdd(&u.hist[w2 >> 19], 1u);
        atomicAdd(&u.hist[(w3 & 0xFFFFu) >> 3], 1u);
        atomicAdd(&u.hist[w3 >> 19], 1u);
    }
    __syncthreads();

    // Phase B: find bin T containing the rank-512 boundary (from the top)
    {
        unsigned s = 0;
        int base = tid * 32;
#pragma unroll 8
        for (int j = 0; j < 32; ++j) s += u.hist[base + j];
        seg[tid] = s;
    }
    __syncthreads();
    if (tid == 0) {
        unsigned cum = 0;
        int T = 0;
        for (int sg = 255; sg >= 0; --sg) {
            if (cum + seg[sg] >= (unsigned)kK) {
                for (int bi = sg * 32 + 31; bi >= sg * 32; --bi) {
                    if (cum + u.hist[bi] >= (unsigned)kK) { T = bi; break; }
                    cum += u.hist[bi];
                }
                break;
            }
            cum += seg[sg];
        }
        // cum = count in bins > T (< 512)
        unsigned histT1 = (T + 1 < HB) ? u.hist[T + 1] : 0u;
        int above = (int)(cum - histT1);  // count in bins >= T+2
        s_T = T;
        s_need = kK - above;
    }
    __syncthreads();
    int T = s_T;
    int binLo = (T > 0) ? T - 1 : 0;

    // Phase C: classify (auto-select / candidate)
    for (int i = tid; i < kN / 8; i += 256) {
        uint4 v = krow4[i];
        unsigned ww[4] = {v.x, v.y, v.z, v.w};
#pragma unroll
        for (int c = 0; c < 4; ++c) {
            int nb0 = i * 8 + c * 2;
            int bin0 = (int)((ww[c] & 0xFFFFu) >> 3);
            int bin1 = (int)(ww[c] >> 19);
            if (bin0 > T + 1) {
                int p = atomicAdd(&s_cnt, 1);
                if (p < kK) sel[p] = nb0;
            } else if (bin0 >= binLo) {
                int p = atomicAdd(&s_cc, 1);
                if (p < CAP) u.s2.cand[p] = (unsigned)nb0;
            }
            if (bin1 > T + 1) {
                int p = atomicAdd(&s_cnt, 1);
                if (p < kK) sel[p] = nb0 + 1;
            } else if (bin1 >= binLo) {
                int p = atomicAdd(&s_cc, 1);
                if (p < CAP) u.s2.cand[p] = (unsigned)(nb0 + 1);
            }
        }
    }
    __syncthreads();
    int cc = min(s_cc, CAP);
    int need = s_need;

    // Phase D: exact f32 recompute of candidates (numpy accumulation order);
    // pack (monokey, ~idx) so desc sort == numpy top_k tie-breaking.
    for (int i = tid; i < cc; i += 256) {
        int idx = (int)u.s2.cand[i];
        const float* nr = neg + ((size_t)b * kN + idx) * kD;
        float acc = 0.f;
#pragma unroll 8
        for (int d4 = 0; d4 < kD; d4 += 4) {
            float4 nv = *(const float4*)(nr + d4);
            acc = fmaf(nv.x, fr[d4 + 0], acc);
            acc = fmaf(nv.y, fr[d4 + 1], acc);
            acc = fmaf(nv.z, fr[d4 + 2], acc);
            acc = fmaf(nv.w, fr[d4 + 3], acc);
        }
        u.s2.vals[i] = ((unsigned long long)mono32(acc) << 32) |
                       (unsigned long long)(0xFFFFFFFFu - (unsigned)idx);
    }
    int ns = 1;
    while (ns < cc) ns <<= 1;
    if (ns < 2) ns = 2;
    for (int i = cc + tid; i < ns; i += 256) u.s2.vals[i] = 0ull;
    __syncthreads();

    // Phase E: bitonic sort ascending (take from the tail)
    for (int kk = 2; kk <= ns; kk <<= 1) {
        for (int jj = kk >> 1; jj > 0; jj >>= 1) {
            for (int i = tid; i < ns; i += 256) {
                int ixj = i ^ jj;
                if (ixj > i) {
                    unsigned long long a0 = u.s2.vals[i];
                    unsigned long long a1 = u.s2.vals[ixj];
                    bool up = ((i & kk) == 0);
                    if ((a0 > a1) == up) {
                        u.s2.vals[i] = a1;
                        u.s2.vals[ixj] = a0;
                    }
                }
            }
            __syncthreads();
        }
    }

    // top `need` fill sel[above..512)
    for (int r = tid; r < need; r += 256) {
        unsigned long long v = u.s2.vals[ns - 1 - r];
        sel[(kK - need) + r] = (int)(0xFFFFFFFFu - (unsigned)(v & 0xFFFFFFFFull));
    }
    __syncthreads();

    // Phase F: bilinear scores for the 512 selected (exact f32, numpy order)
    const float4* nb4 = (const float4*)(neg + (size_t)b * kN * kD);
#pragma unroll
    for (int r = 0; r < 2; ++r) {
        int k = r * 256 + tid;
        int idx = sel[k];
        if (idx < 0) idx = 0;
        if (idx >= kN) idx = kN - 1;
        const float4* rp = nb4 + (size_t)idx * (kD / 4);
        float acc = 0.f;
#pragma unroll 8
        for (int d4 = 0; d4 < kD / 4; ++d4) {
            float4 nv = rp[d4];
            float4 pv = *(const float4*)&pw[d4 * 4];
            acc = fmaf(nv.x, pv.x, acc);
            acc = fmaf(nv.y, pv.y, acc);
            acc = fmaf(nv.z, pv.z, acc);
            acc = fmaf(nv.w, pv.w, acc);
        }
        scores[k] = acc;
    }
    __syncthreads();

    // Phase G: out = sum softmax(scale*s) * s + bias
    float spv = scale_p[0];
    float scale = (spv > 20.f) ? spv : log1pf(__expf(spv));
    int lane = tid & 63;
    int wid = tid >> 6;

    float s0 = scores[tid];
    float s1 = scores[tid + 256];
    float lm = fmaxf(scale * s0, scale * s1);
#pragma unroll
    for (int o = 32; o > 0; o >>= 1) lm = fmaxf(lm, __shfl_down(lm, o));
    if (lane == 0) rbuf[wid] = lm;
    __syncthreads();
    if (tid == 0) s_m = fmaxf(fmaxf(rbuf[0], rbuf[1]), fmaxf(rbuf[2], rbuf[3]));
    __syncthreads();
    float mx = s_m;
    float e0 = __expf(scale * s0 - mx);
    float e1 = __expf(scale * s1 - mx);
    float ln = e0 * s0 + e1 * s1;
    float ld = e0 + e1;
#pragma unroll
    for (int o = 32; o > 0; o >>= 1) {
        ln += __shfl_down(ln, o);
        ld += __shfl_down(ld, o);
    }
    if (lane == 0) { rbuf[wid] = ln; rbuf[4 + wid] = ld; }
    __syncthreads();
    if (tid == 0) {
        float num = rbuf[0] + rbuf[1] + rbuf[2] + rbuf[3];
        float den = rbuf[4] + rbuf[5] + rbuf[6] + rbuf[7];
        out[row] = num / den + bias_p[0];
    }
}

extern "C" void kernel_launch(void* const* d_in, const int* in_sizes, int n_in,
                              void* d_out, int out_size, void* d_ws, size_t ws_size,
                              hipStream_t stream) {
    const float* fea0 = (const float*)d_in[0];   // [8,100,128]
    const float* neg = (const float*)d_in[1];    // [8,50000,128]
    const float* W = (const float*)d_in[2];      // [128,128]
    const float* bias = (const float*)d_in[3];   // scalar
    const float* scale = (const float*)d_in[4];  // scalar
    float* out = (float*)d_out;                  // [800]

    // ws: keys u16 [800*50000] = 80,000,000 B | posW f32 [800*128] | feab u16 [800*128]
    unsigned short* keys = (unsigned short*)d_ws;
    float* posW = (float*)((char*)d_ws + (size_t)kRows * kN * sizeof(unsigned short));
    unsigned short* feab =
        (unsigned short*)((char*)posW + (size_t)kRows * kD * sizeof(float));

    posw_kernel<<<kRows, kD, 0, stream>>>(fea0, W, posW, feab);
    sim_kernel<<<dim3((kN + SIM_TN - 1) / SIM_TN, kB), 256, 0, stream>>>(feab, neg, keys);
    select_kernel<<<kRows, 256, 0, stream>>>(fea0, neg, posW, keys, bias, scale, out);
}